// Round 20
// baseline (91.257 us; speedup 1.0000x reference)
//
#include <hip/hip_runtime.h>
#include <math.h>

// NoisyTopkRouter: B=4,S=4096,D=2048,E=64,TOP_K=8
//   gemm_k1: r20 = r19 macro-tile (BM=256, 512 thr) + KSPLIT=8 -> grid 512 =
//   2 blocks/CU (r16/r14 evidence: block interleave hides the per-step
//   stage+drain stall; r19 at 1 blk/CU had nothing to hide it) + x-staging
//   remap to 8-lines/instr coalescing (was 32). LDS addresses unchanged ->
//   numerics identical to r19. epi_fast sums nsplit partials; refine frozen.

#define KDIM 2048
#define NEXP 64
#define BM 256
#define KB 32
#define TAU 1.5e-4f

typedef __attribute__((ext_vector_type(8))) short short8v;
typedef __attribute__((ext_vector_type(16))) float f32x16;

__device__ __forceinline__ void bsplit(float v, ushort& h, ushort& l) {
  unsigned u = __float_as_uint(v);
  unsigned hu = (u + 0x8000u) & 0xFFFF0000u;
  h = (ushort)(hu >> 16);
  float r = v - __uint_as_float(hu);
  l = (ushort)((__float_as_uint(r) + 0x8000u) >> 16);
}

// Wpk[blk 0..63][col 0..127][unit' 0..7][8 bf16]; unit' = (p*4+u) ^ (col&7)
__global__ __launch_bounds__(256)
void convert_w(const float* __restrict__ Wr, const float* __restrict__ Wn,
               ushort* __restrict__ Wpk, int* __restrict__ flagcnt) {
  if (blockIdx.x == 0 && threadIdx.x == 0) *flagcnt = 0;
  const int g = blockIdx.x * 256 + threadIdx.x;   // 32768 threads
  const int col = g >> 8;
  const int rem = g & 255;
  const int blk = rem >> 2;
  const int u   = rem & 3;
  const float* srcrow = (col < NEXP) ? (Wr + (size_t)col * KDIM)
                                     : (Wn + (size_t)(col - NEXP) * KDIM);
  const int k = blk * 32 + u * 8;
  const float4 v0 = *(const float4*)(srcrow + k);
  const float4 v1 = *(const float4*)(srcrow + k + 4);
  short8v hv, lv; ushort h, l;
  bsplit(v0.x, h, l); hv[0] = h; lv[0] = l;
  bsplit(v0.y, h, l); hv[1] = h; lv[1] = l;
  bsplit(v0.z, h, l); hv[2] = h; lv[2] = l;
  bsplit(v0.w, h, l); hv[3] = h; lv[3] = l;
  bsplit(v1.x, h, l); hv[4] = h; lv[4] = l;
  bsplit(v1.y, h, l); hv[5] = h; lv[5] = l;
  bsplit(v1.z, h, l); hv[6] = h; lv[6] = l;
  bsplit(v1.w, h, l); hv[7] = h; lv[7] = l;
  const size_t base = (size_t)blk * 8192 + (size_t)col * 64;
  *(short8v*)(Wpk + base + (size_t)((u)     ^ (col & 7)) * 8) = hv;
  *(short8v*)(Wpk + base + (size_t)((4 + u) ^ (col & 7)) * 8) = lv;
}

__global__ __launch_bounds__(512, 4)
void gemm_k1(const float* __restrict__ x, const ushort* __restrict__ Wpk,
             float* __restrict__ partials, int M)   // [nsplit][M][128]
{
  __shared__ ushort Bb[2][8192];    // 2 x 16KB  [col128][unit'8][8]
  __shared__ ushort Ab[2][16384];   // 2 x 32KB  [row256][unit'8][8]

  const int tid   = threadIdx.x;
  const int row0  = blockIdx.x * BM;
  const int ks    = blockIdx.y;
  const int nspl  = gridDim.y;
  const int kchunk = KDIM / nspl;
  const int NKB   = kchunk / KB;
  const ushort* Wpkh = Wpk + (size_t)ks * NKB * 8192;

  const int wid  = tid >> 6;            // 0..7 row-group (32 rows)
  const int lane = tid & 63;
  const int l31  = lane & 31;
  const int kg   = lane >> 5;

  // x stage map (coalesced): load j -> idx = j*512+tid, row = idx>>3,
  // k4 = (idx&7)*4. 8 consecutive lanes cover one row's 128B line.
  const float* xbase = x + (size_t)ks * kchunk;

  // fragment read constants (r19 layout, proven)
  const int rr = wid * 32 + l31;
  const int fa = ((l31 & 1) << 2) | ((l31 >> 1) & 3);

  f32x16 acc[4];
#pragma unroll
  for (int c = 0; c < 4; ++c) acc[c] = (f32x16){0,0,0,0,0,0,0,0,0,0,0,0,0,0,0,0};

  // per-thread write constants for the 4 staged float4s (compile-time j)
#define AROW(j)  (((j) * 512 + tid) >> 3)
#define AK4(j)   ((((j) * 512 + tid) & 7) * 4)
#define AFW(j)   (((AROW(j) & 1) << 2) | ((AROW(j) >> 1) & 3))
#define AUNIT(j) (AK4(j) >> 3)
#define AHALF(j) ((AK4(j) >> 2) & 1)

#define SPLIT_STORE(j, xq, buf)                                               \
  do {                                                                        \
    ushort4 hq, lq;                                                           \
    bsplit(xq.x, hq.x, lq.x); bsplit(xq.y, hq.y, lq.y);                       \
    bsplit(xq.z, hq.z, lq.z); bsplit(xq.w, hq.w, lq.w);                       \
    *(ushort4*)&Ab[buf][AROW(j) * 64 + ((AUNIT(j)) ^ AFW(j)) * 8 +            \
                        AHALF(j) * 4] = hq;                                   \
    *(ushort4*)&Ab[buf][AROW(j) * 64 + ((4 + AUNIT(j)) ^ AFW(j)) * 8 +        \
                        AHALF(j) * 4] = lq;                                   \
  } while (0)

#define XADDR(j, s) (xbase + (size_t)(row0 + AROW(j)) * KDIM + (s) * KB + AK4(j))

  // prologue: stage step 0
#pragma unroll
  for (int j = 0; j < 2; ++j) {
    const int idx = j * 512 + tid;
    __builtin_amdgcn_global_load_lds(
        (const __attribute__((address_space(1))) void*)(Wpkh + (size_t)idx * 8),
        (__attribute__((address_space(3))) void*)(&Bb[0][(size_t)idx * 8]),
        16, 0, 0);
  }
  {
    float4 xq0 = *(const float4*)XADDR(0, 0);
    float4 xq1 = *(const float4*)XADDR(1, 0);
    float4 xq2 = *(const float4*)XADDR(2, 0);
    float4 xq3 = *(const float4*)XADDR(3, 0);
    SPLIT_STORE(0, xq0, 0);
    SPLIT_STORE(1, xq1, 0);
    SPLIT_STORE(2, xq2, 0);
    SPLIT_STORE(3, xq3, 0);
  }
  __syncthreads();

  for (int s = 0; s < NKB; ++s) {
    const int cur = s & 1, nxt = cur ^ 1;
    float4 xq0, xq1, xq2, xq3;
    if (s + 1 < NKB) {
#pragma unroll
      for (int j = 0; j < 2; ++j) {
        const int idx = j * 512 + tid;
        __builtin_amdgcn_global_load_lds(
            (const __attribute__((address_space(1))) void*)
                (Wpkh + (size_t)(s + 1) * 8192 + (size_t)idx * 8),
            (__attribute__((address_space(3))) void*)
                (&Bb[nxt][(size_t)idx * 8]), 16, 0, 0);
      }
      xq0 = *(const float4*)XADDR(0, s + 1);
      xq1 = *(const float4*)XADDR(1, s + 1);
      xq2 = *(const float4*)XADDR(2, s + 1);
      xq3 = *(const float4*)XADDR(3, s + 1);
    }
    __builtin_amdgcn_sched_barrier(0);   // pin staging issue before compute

    // ---- compute K-block s: 32 rows x 128 cols per wave ----
#pragma unroll
    for (int kk = 0; kk < 2; ++kk) {
      const int u = kk * 2 + kg;
      const short8v ah = *(const short8v*)&Ab[cur][rr * 64 + ((u)     ^ fa) * 8];
      const short8v al = *(const short8v*)&Ab[cur][rr * 64 + ((4 + u) ^ fa) * 8];
#pragma unroll
      for (int c = 0; c < 4; ++c) {
        const int colB = c * 32 + l31;
        const int fb   = colB & 7;
        const short8v bh = *(const short8v*)&Bb[cur][colB * 64 + ((u)     ^ fb) * 8];
        const short8v bl = *(const short8v*)&Bb[cur][colB * 64 + ((4 + u) ^ fb) * 8];
        acc[c] = __builtin_amdgcn_mfma_f32_32x32x16_bf16(ah, bh, acc[c], 0, 0, 0);
        acc[c] = __builtin_amdgcn_mfma_f32_32x32x16_bf16(ah, bl, acc[c], 0, 0, 0);
        acc[c] = __builtin_amdgcn_mfma_f32_32x32x16_bf16(al, bh, acc[c], 0, 0, 0);
      }
    }

    if (s + 1 < NKB) {
      SPLIT_STORE(0, xq0, nxt);
      SPLIT_STORE(1, xq1, nxt);
      SPLIT_STORE(2, xq2, nxt);
      SPLIT_STORE(3, xq3, nxt);
    }
    __syncthreads();
  }
#undef SPLIT_STORE
#undef XADDR
#undef AROW
#undef AK4
#undef AFW
#undef AUNIT
#undef AHALF

  // C/D layout (32x32): col = lane&31, row = (reg&3) + 8*(reg>>2) + 4*kg
  float* dst = partials + (size_t)ks * M * 128;
#pragma unroll
  for (int c = 0; c < 4; ++c)
#pragma unroll
    for (int reg = 0; reg < 16; ++reg) {
      const int row = (reg & 3) + 8 * (reg >> 2) + 4 * kg;
      dst[(size_t)(row0 + wid * 32 + row) * 128 + c * 32 + l31] = acc[c][reg];
    }
}

// one wave per token: fast path; sums nsplit partials inline
__global__ __launch_bounds__(512, 4)
void epi_fast(const float* __restrict__ partials, int M, int nsplit,
              const float* __restrict__ br, const float* __restrict__ bn,
              const float* __restrict__ noise,
              float* __restrict__ out_w, float* __restrict__ out_i,
              float* __restrict__ out_s,
              int* __restrict__ flagcnt, int* __restrict__ flaglist)
{
  const int wid  = threadIdx.x >> 6;
  const int lane = threadIdx.x & 63;
  const int t    = blockIdx.x * 8 + wid;

  float sr = 0.f, sn = 0.f;
  for (int p = 0; p < nsplit; ++p) {
    sr += partials[(size_t)p * M * 128 + (size_t)t * 128 + lane];
    sn += partials[(size_t)p * M * 128 + (size_t)t * 128 + 64 + lane];
  }
  const float z  = sn + bn[lane];
  const float sp = fmaxf(z, 0.f) + log1pf(expf(-fabsf(z)));
  const float v  = sr + br[lane] + noise[(size_t)t * NEXP + lane] * sp;

  float m = v;
#pragma unroll
  for (int d = 32; d; d >>= 1) m = fmaxf(m, __shfl_xor(m, d));
  const float p = expf(v - m);
  float sum = p;
#pragma unroll
  for (int d = 32; d; d >>= 1) sum += __shfl_xor(sum, d);
  out_s[(size_t)t * NEXP + lane] = p / sum;

  float cur = v;
  float vals9[9]; int idx9[9];
#pragma unroll
  for (int it = 0; it < 9; ++it) {
    float mx = cur;
#pragma unroll
    for (int d = 32; d; d >>= 1) mx = fmaxf(mx, __shfl_xor(mx, d));
    const unsigned long long b = __ballot(cur == mx);
    const int li = __ffsll(b) - 1;                 // ties -> lowest index
    vals9[it] = mx; idx9[it] = li;
    if (lane == li) cur = -INFINITY;
  }
  bool flagged = false;
#pragma unroll
  for (int q = 0; q < 8; ++q) flagged |= (vals9[q] - vals9[q + 1] < TAU);

  if (flagged) {
    if (lane == 0) {
      const int s = atomicAdd(flagcnt, 1);
      flaglist[s] = t;
    }
    return;                                        // refine_* writes outputs
  }

  float pt[8]; float ws = 0.f;
#pragma unroll
  for (int q = 0; q < 8; ++q) { pt[q] = expf(vals9[q] - m); ws += pt[q]; }
  if (lane < 8) {
    out_w[(size_t)t * 8 + lane] = pt[lane] / ws;
    out_i[(size_t)t * 8 + lane] = (float)idx9[lane];
  }
}

// one WAVE per (flagged token, expert): nf*64 wave-jobs, grid-strided
__global__ __launch_bounds__(512)
void refine_dots(const float* __restrict__ x,
                 const float* __restrict__ Wr, const float* __restrict__ Wn,
                 const float* __restrict__ br, const float* __restrict__ bn,
                 const float* __restrict__ noise,
                 const int* __restrict__ flagcnt, const int* __restrict__ flaglist,
                 double* __restrict__ nv64)
{
  const int nf    = *flagcnt;
  const int lane  = threadIdx.x & 63;
  const int wslot = (blockIdx.x * 512 + threadIdx.x) >> 6;
  const int nwav  = (gridDim.x * 512) >> 6;
  const int total = nf * 64;

  for (int w = wslot; w < total; w += nwav) {
    const int i = w >> 6, e = w & 63;
    const int t = flaglist[i];
    const float* xr  = x  + (size_t)t * KDIM + lane * 4;
    const float* wrr = Wr + (size_t)e * KDIM + lane * 4;
    const float* wnr = Wn + (size_t)e * KDIM + lane * 4;
    double a0 = 0, a1 = 0, c0 = 0, c1 = 0;
#pragma unroll
    for (int q = 0; q < 8; ++q) {
      const float4 xv = *(const float4*)(xr  + q * 256);
      const float4 wv = *(const float4*)(wrr + q * 256);
      const float4 nv = *(const float4*)(wnr + q * 256);
      a0 = fma((double)xv.x, (double)wv.x, a0);
      a1 = fma((double)xv.y, (double)wv.y, a1);
      a0 = fma((double)xv.z, (double)wv.z, a0);
      a1 = fma((double)xv.w, (double)wv.w, a1);
      c0 = fma((double)xv.x, (double)nv.x, c0);
      c1 = fma((double)xv.y, (double)nv.y, c1);
      c0 = fma((double)xv.z, (double)nv.z, c0);
      c1 = fma((double)xv.w, (double)nv.w, c1);
    }
    double ar = a0 + a1, an = c0 + c1;
#pragma unroll
    for (int d = 32; d; d >>= 1) {
      ar += __shfl_xor(ar, d);
      an += __shfl_xor(an, d);
    }
    if (lane == 0) {
      const double rte = ar + (double)br[e];
      const double zz  = an + (double)bn[e];
      const double spd = fmax(zz, 0.0) + log1p(exp(-fabs(zz)));
      nv64[(size_t)i * 64 + e] = rte + (double)noise[(size_t)t * NEXP + e] * spd;
    }
  }
}

// one wave per flagged token: proven fp64 softmax/top-8 tail
__global__ __launch_bounds__(512)
void refine_final(const double* __restrict__ nv64,
                  const int* __restrict__ flagcnt, const int* __restrict__ flaglist,
                  float* __restrict__ out_w, float* __restrict__ out_i,
                  float* __restrict__ out_s)
{
  const int nf    = *flagcnt;
  const int lane  = threadIdx.x & 63;
  const int wslot = (blockIdx.x * 512 + threadIdx.x) >> 6;
  const int nwav  = (gridDim.x * 512) >> 6;

  for (int i = wslot; i < nf; i += nwav) {
    const int t = flaglist[i];
    const double v64 = nv64[(size_t)i * 64 + lane];
    double md = v64;
#pragma unroll
    for (int d = 32; d; d >>= 1) md = fmax(md, __shfl_xor(md, d));
    const double pe = exp(v64 - md);
    double sd = pe;
#pragma unroll
    for (int d = 32; d; d >>= 1) sd += __shfl_xor(sd, d);
    out_s[(size_t)t * NEXP + lane] = (float)(pe / sd);

    double curd = v64;
    double pv8[8]; int pi8[8]; double wsd = 0.0;
#pragma unroll
    for (int it = 0; it < 8; ++it) {
      double mx = curd;
#pragma unroll
      for (int d = 32; d; d >>= 1) mx = fmax(mx, __shfl_xor(mx, d));
      const unsigned long long b = __ballot(curd == mx);
      const int li = __ffsll(b) - 1;
      pv8[it] = __shfl(pe, li); pi8[it] = li; wsd += pv8[it];
      if (lane == li) curd = -1e300;
    }
    if (lane < 8) {
      out_w[(size_t)t * 8 + lane] = (float)(pv8[lane] / wsd);
      out_i[(size_t)t * 8 + lane] = (float)pi8[lane];
    }
  }
}

extern "C" void kernel_launch(void* const* d_in, const int* in_sizes, int n_in,
                              void* d_out, int out_size, void* d_ws, size_t ws_size,
                              hipStream_t stream) {
  const float* x     = (const float*)d_in[0];
  const float* Wr    = (const float*)d_in[1];
  const float* br    = (const float*)d_in[2];
  const float* Wn    = (const float*)d_in[3];
  const float* bn    = (const float*)d_in[4];
  const float* noise = (const float*)d_in[5];

  const int M = in_sizes[0] / KDIM;                  // 16384 tokens

  // KSPLIT=8 -> grid 512 = 2 blocks/CU (ws is ~536 MB per the fill kernels).
  const size_t fixed = (1 << 20) + ((size_t)M + 1) * 4;
  int nsplit = 2;
  if (ws_size >= (size_t)8 * M * 128 * 4 + fixed) nsplit = 8;
  else if (ws_size >= (size_t)4 * M * 128 * 4 + fixed) nsplit = 4;

  float*  partials = (float*)d_ws;                   // [nsplit][M][128]
  double* nv64     = (double*)d_ws;                  // aliases (dead after epi)
  ushort* Wpk      = (ushort*)(partials + (size_t)nsplit * M * 128);  // 1 MB
  int*    flagcnt  = (int*)(Wpk + (size_t)64 * 8192);
  int*    flaglist = flagcnt + 1;

  float* out   = (float*)d_out;
  float* out_w = out;                                // [M,8]
  float* out_i = out + (size_t)M * 8;                // [M,8] indices as floats
  float* out_s = out + (size_t)M * 16;               // [M,64]

  convert_w<<<dim3(128), dim3(256), 0, stream>>>(Wr, Wn, Wpk, flagcnt);
  gemm_k1<<<dim3(M / BM, nsplit), dim3(512), 0, stream>>>(x, Wpk, partials, M);
  epi_fast<<<dim3(M / 8), dim3(512), 0, stream>>>(partials, M, nsplit, br, bn,
                                                  noise, out_w, out_i, out_s,
                                                  flagcnt, flaglist);
  refine_dots<<<dim3(1024), dim3(512), 0, stream>>>(x, Wr, Wn, br, bn, noise,
                                                    flagcnt, flaglist, nv64);
  refine_final<<<dim3(256), dim3(512), 0, stream>>>(nv64, flagcnt, flaglist,
                                                    out_w, out_i, out_s);
}

// Round 21
// 82.215 us; speedup vs baseline: 1.1100x; 1.1100x over previous
//
#include <hip/hip_runtime.h>
#include <math.h>

// NoisyTopkRouter: B=4,S=4096,D=2048,E=64,TOP_K=8
//   gemm_k1: r21 = r19 base (BM=256, KSPLIT=4, grid 256 = 1 blk/CU) +
//   counted-vmcnt depth-2 pipeline, 3 LDS buffer sets (144 KB), raw s_barrier
//   (never __syncthreads -> never vmcnt(0) in steady state). r17's mechanism
//   with its two confounds removed (occupancy structure kept; bsplit stays
//   produce-side). Batch = 6 VMEM (2 B-glds + 4 x reg loads); steady wait
//   vmcnt(6) = batch s+1 home while s+2 flies under compute.
//   convert_w / epi_fast / refine_dots / refine_final frozen (r12/r19).

#define KDIM 2048
#define NEXP 64
#define BM 256
#define KB 32
#define TAU 1.5e-4f

typedef __attribute__((ext_vector_type(8))) short short8v;
typedef __attribute__((ext_vector_type(16))) float f32x16;

__device__ __forceinline__ void bsplit(float v, ushort& h, ushort& l) {
  unsigned u = __float_as_uint(v);
  unsigned hu = (u + 0x8000u) & 0xFFFF0000u;
  h = (ushort)(hu >> 16);
  float r = v - __uint_as_float(hu);
  l = (ushort)((__float_as_uint(r) + 0x8000u) >> 16);
}

// Wpk[blk 0..63][col 0..127][unit' 0..7][8 bf16]; unit' = (p*4+u) ^ (col&7)
__global__ __launch_bounds__(256)
void convert_w(const float* __restrict__ Wr, const float* __restrict__ Wn,
               ushort* __restrict__ Wpk, int* __restrict__ flagcnt) {
  if (blockIdx.x == 0 && threadIdx.x == 0) *flagcnt = 0;
  const int g = blockIdx.x * 256 + threadIdx.x;   // 32768 threads
  const int col = g >> 8;
  const int rem = g & 255;
  const int blk = rem >> 2;
  const int u   = rem & 3;
  const float* srcrow = (col < NEXP) ? (Wr + (size_t)col * KDIM)
                                     : (Wn + (size_t)(col - NEXP) * KDIM);
  const int k = blk * 32 + u * 8;
  const float4 v0 = *(const float4*)(srcrow + k);
  const float4 v1 = *(const float4*)(srcrow + k + 4);
  short8v hv, lv; ushort h, l;
  bsplit(v0.x, h, l); hv[0] = h; lv[0] = l;
  bsplit(v0.y, h, l); hv[1] = h; lv[1] = l;
  bsplit(v0.z, h, l); hv[2] = h; lv[2] = l;
  bsplit(v0.w, h, l); hv[3] = h; lv[3] = l;
  bsplit(v1.x, h, l); hv[4] = h; lv[4] = l;
  bsplit(v1.y, h, l); hv[5] = h; lv[5] = l;
  bsplit(v1.z, h, l); hv[6] = h; lv[6] = l;
  bsplit(v1.w, h, l); hv[7] = h; lv[7] = l;
  const size_t base = (size_t)blk * 8192 + (size_t)col * 64;
  *(short8v*)(Wpk + base + (size_t)((u)     ^ (col & 7)) * 8) = hv;
  *(short8v*)(Wpk + base + (size_t)((4 + u) ^ (col & 7)) * 8) = lv;
}

__global__ __launch_bounds__(512, 1)
void gemm_k1(const float* __restrict__ x, const ushort* __restrict__ Wpk,
             float* __restrict__ partials, int M)   // [nsplit][M][128]
{
  __shared__ ushort Bb[3][8192];    // 3 x 16KB
  __shared__ ushort Ab[3][16384];   // 3 x 32KB   (total 144 KB)

  const int tid   = threadIdx.x;
  const int row0  = blockIdx.x * BM;
  const int ks    = blockIdx.y;
  const int nspl  = gridDim.y;
  const int kchunk = KDIM / nspl;
  const int NKB   = kchunk / KB;               // 16 at nsplit=4
  const ushort* Wpkh = Wpk + (size_t)ks * NKB * 8192;

  const int wid  = tid >> 6;
  const int lane = tid & 63;
  const int l31  = lane & 31;
  const int kg   = lane >> 5;

  const float* xbase = x + (size_t)ks * kchunk;

  const int rr = wid * 32 + l31;
  const int fa = ((l31 & 1) << 2) | ((l31 >> 1) & 3);

  f32x16 acc[4];
#pragma unroll
  for (int c = 0; c < 4; ++c) acc[c] = (f32x16){0,0,0,0,0,0,0,0,0,0,0,0,0,0,0,0};

#define AROW(j)  (((j) * 512 + tid) >> 3)
#define AK4(j)   ((((j) * 512 + tid) & 7) * 4)
#define AFW(j)   (((AROW(j) & 1) << 2) | ((AROW(j) >> 1) & 3))
#define AUNIT(j) (AK4(j) >> 3)
#define AHALF(j) ((AK4(j) >> 2) & 1)

#define SPLIT_STORE(j, xq, buf)                                               \
  do {                                                                        \
    ushort4 hq, lq;                                                           \
    bsplit(xq.x, hq.x, lq.x); bsplit(xq.y, hq.y, lq.y);                       \
    bsplit(xq.z, hq.z, lq.z); bsplit(xq.w, hq.w, lq.w);                       \
    *(ushort4*)&Ab[buf][AROW(j) * 64 + ((AUNIT(j)) ^ AFW(j)) * 8 +            \
                        AHALF(j) * 4] = hq;                                   \
    *(ushort4*)&Ab[buf][AROW(j) * 64 + ((4 + AUNIT(j)) ^ AFW(j)) * 8 +        \
                        AHALF(j) * 4] = lq;                                   \
  } while (0)

#define XADDR(j, s) (xbase + (size_t)(row0 + AROW(j)) * KDIM + (s) * KB + AK4(j))

#define ISSUE_B(t, bidx)                                                      \
  do {                                                                        \
    _Pragma("unroll")                                                         \
    for (int j = 0; j < 2; ++j) {                                             \
      const int idx = j * 512 + tid;                                          \
      __builtin_amdgcn_global_load_lds(                                       \
          (const __attribute__((address_space(1))) void*)                     \
              (Wpkh + (size_t)(t) * 8192 + (size_t)idx * 8),                  \
          (__attribute__((address_space(3))) void*)                           \
              (&Bb[bidx][(size_t)idx * 8]), 16, 0, 0);                        \
    }                                                                         \
  } while (0)

#define COMPUTE(bc)                                                           \
  do {                                                                        \
    _Pragma("unroll")                                                         \
    for (int kk = 0; kk < 2; ++kk) {                                          \
      const int u = kk * 2 + kg;                                              \
      const short8v ah = *(const short8v*)&Ab[bc][rr * 64 + ((u)     ^ fa) * 8]; \
      const short8v al = *(const short8v*)&Ab[bc][rr * 64 + ((4 + u) ^ fa) * 8]; \
      _Pragma("unroll")                                                       \
      for (int c = 0; c < 4; ++c) {                                           \
        const int colB = c * 32 + l31;                                        \
        const int fb   = colB & 7;                                            \
        const short8v bh = *(const short8v*)&Bb[bc][colB * 64 + ((u)     ^ fb) * 8]; \
        const short8v bl = *(const short8v*)&Bb[bc][colB * 64 + ((4 + u) ^ fb) * 8]; \
        acc[c] = __builtin_amdgcn_mfma_f32_32x32x16_bf16(ah, bh, acc[c], 0, 0, 0);  \
        acc[c] = __builtin_amdgcn_mfma_f32_32x32x16_bf16(ah, bl, acc[c], 0, 0, 0);  \
        acc[c] = __builtin_amdgcn_mfma_f32_32x32x16_bf16(al, bh, acc[c], 0, 0, 0);  \
      }                                                                       \
    }                                                                         \
  } while (0)

  float4 xe0, xe1, xe2, xe3;   // even reg set (batches t with t%2==0)
  float4 xo0, xo1, xo2, xo3;   // odd  reg set

  // ---- prologue: batches 0 (->set e) and 1 (->set o) in flight ----
  ISSUE_B(0, 0);
  xe0 = *(const float4*)XADDR(0, 0);
  xe1 = *(const float4*)XADDR(1, 0);
  xe2 = *(const float4*)XADDR(2, 0);
  xe3 = *(const float4*)XADDR(3, 0);
  ISSUE_B(1, 1);
  xo0 = *(const float4*)XADDR(0, 1);
  xo1 = *(const float4*)XADDR(1, 1);
  xo2 = *(const float4*)XADDR(2, 1);
  xo3 = *(const float4*)XADDR(3, 1);
  __builtin_amdgcn_sched_barrier(0);
  asm volatile("s_waitcnt vmcnt(6)" ::: "memory");   // batch 0 home
  __builtin_amdgcn_sched_barrier(0);
  SPLIT_STORE(0, xe0, 0);
  SPLIT_STORE(1, xe1, 0);
  SPLIT_STORE(2, xe2, 0);
  SPLIT_STORE(3, xe3, 0);
  asm volatile("s_waitcnt lgkmcnt(0)" ::: "memory");
  __builtin_amdgcn_s_barrier();
  __builtin_amdgcn_sched_barrier(0);

  for (int ss = 0; ss < NKB; ss += 2) {
    // ======== even step s = ss: issue(s+2)->set e; consume set o ========
    {
      const int s  = ss;
      const int bc = s % 3, bw = (s + 1) % 3, bi = (s + 2) % 3;
      if (s + 2 < NKB) {
        ISSUE_B(s + 2, bi);
        xe0 = *(const float4*)XADDR(0, s + 2);
        xe1 = *(const float4*)XADDR(1, s + 2);
        xe2 = *(const float4*)XADDR(2, s + 2);
        xe3 = *(const float4*)XADDR(3, s + 2);
      }
      __builtin_amdgcn_sched_barrier(0);
      COMPUTE(bc);
      __builtin_amdgcn_sched_barrier(0);
      if (s + 2 < NKB) {
        asm volatile("s_waitcnt vmcnt(6)" ::: "memory");
      } else if (s + 1 < NKB) {
        asm volatile("s_waitcnt vmcnt(0)" ::: "memory");
      }
      __builtin_amdgcn_sched_barrier(0);
      if (s + 1 < NKB) {
        SPLIT_STORE(0, xo0, bw);
        SPLIT_STORE(1, xo1, bw);
        SPLIT_STORE(2, xo2, bw);
        SPLIT_STORE(3, xo3, bw);
      }
      asm volatile("s_waitcnt lgkmcnt(0)" ::: "memory");
      __builtin_amdgcn_s_barrier();
      __builtin_amdgcn_sched_barrier(0);
    }
    // ======== odd step s = ss+1: issue(s+2)->set o; consume set e ========
    {
      const int s  = ss + 1;
      const int bc = s % 3, bw = (s + 1) % 3, bi = (s + 2) % 3;
      if (s + 2 < NKB) {
        ISSUE_B(s + 2, bi);
        xo0 = *(const float4*)XADDR(0, s + 2);
        xo1 = *(const float4*)XADDR(1, s + 2);
        xo2 = *(const float4*)XADDR(2, s + 2);
        xo3 = *(const float4*)XADDR(3, s + 2);
      }
      __builtin_amdgcn_sched_barrier(0);
      COMPUTE(bc);
      __builtin_amdgcn_sched_barrier(0);
      if (s + 2 < NKB) {
        asm volatile("s_waitcnt vmcnt(6)" ::: "memory");
      } else if (s + 1 < NKB) {
        asm volatile("s_waitcnt vmcnt(0)" ::: "memory");
      }
      __builtin_amdgcn_sched_barrier(0);
      if (s + 1 < NKB) {
        SPLIT_STORE(0, xe0, bw);
        SPLIT_STORE(1, xe1, bw);
        SPLIT_STORE(2, xe2, bw);
        SPLIT_STORE(3, xe3, bw);
      }
      asm volatile("s_waitcnt lgkmcnt(0)" ::: "memory");
      __builtin_amdgcn_s_barrier();
      __builtin_amdgcn_sched_barrier(0);
    }
  }
#undef COMPUTE
#undef ISSUE_B
#undef SPLIT_STORE
#undef XADDR
#undef AROW
#undef AK4
#undef AFW
#undef AUNIT
#undef AHALF

  // C/D layout (32x32): col = lane&31, row = (reg&3) + 8*(reg>>2) + 4*kg
  float* dst = partials + (size_t)ks * M * 128;
#pragma unroll
  for (int c = 0; c < 4; ++c)
#pragma unroll
    for (int reg = 0; reg < 16; ++reg) {
      const int row = (reg & 3) + 8 * (reg >> 2) + 4 * kg;
      dst[(size_t)(row0 + wid * 32 + row) * 128 + c * 32 + l31] = acc[c][reg];
    }
}

// one wave per token: fast path; sums nsplit partials inline
__global__ __launch_bounds__(512, 4)
void epi_fast(const float* __restrict__ partials, int M, int nsplit,
              const float* __restrict__ br, const float* __restrict__ bn,
              const float* __restrict__ noise,
              float* __restrict__ out_w, float* __restrict__ out_i,
              float* __restrict__ out_s,
              int* __restrict__ flagcnt, int* __restrict__ flaglist)
{
  const int wid  = threadIdx.x >> 6;
  const int lane = threadIdx.x & 63;
  const int t    = blockIdx.x * 8 + wid;

  float sr = 0.f, sn = 0.f;
  for (int p = 0; p < nsplit; ++p) {
    sr += partials[(size_t)p * M * 128 + (size_t)t * 128 + lane];
    sn += partials[(size_t)p * M * 128 + (size_t)t * 128 + 64 + lane];
  }
  const float z  = sn + bn[lane];
  const float sp = fmaxf(z, 0.f) + log1pf(expf(-fabsf(z)));
  const float v  = sr + br[lane] + noise[(size_t)t * NEXP + lane] * sp;

  float m = v;
#pragma unroll
  for (int d = 32; d; d >>= 1) m = fmaxf(m, __shfl_xor(m, d));
  const float p = expf(v - m);
  float sum = p;
#pragma unroll
  for (int d = 32; d; d >>= 1) sum += __shfl_xor(sum, d);
  out_s[(size_t)t * NEXP + lane] = p / sum;

  float cur = v;
  float vals9[9]; int idx9[9];
#pragma unroll
  for (int it = 0; it < 9; ++it) {
    float mx = cur;
#pragma unroll
    for (int d = 32; d; d >>= 1) mx = fmaxf(mx, __shfl_xor(mx, d));
    const unsigned long long b = __ballot(cur == mx);
    const int li = __ffsll(b) - 1;                 // ties -> lowest index
    vals9[it] = mx; idx9[it] = li;
    if (lane == li) cur = -INFINITY;
  }
  bool flagged = false;
#pragma unroll
  for (int q = 0; q < 8; ++q) flagged |= (vals9[q] - vals9[q + 1] < TAU);

  if (flagged) {
    if (lane == 0) {
      const int s = atomicAdd(flagcnt, 1);
      flaglist[s] = t;
    }
    return;                                        // refine_* writes outputs
  }

  float pt[8]; float ws = 0.f;
#pragma unroll
  for (int q = 0; q < 8; ++q) { pt[q] = expf(vals9[q] - m); ws += pt[q]; }
  if (lane < 8) {
    out_w[(size_t)t * 8 + lane] = pt[lane] / ws;
    out_i[(size_t)t * 8 + lane] = (float)idx9[lane];
  }
}

// one WAVE per (flagged token, expert): nf*64 wave-jobs, grid-strided
__global__ __launch_bounds__(512)
void refine_dots(const float* __restrict__ x,
                 const float* __restrict__ Wr, const float* __restrict__ Wn,
                 const float* __restrict__ br, const float* __restrict__ bn,
                 const float* __restrict__ noise,
                 const int* __restrict__ flagcnt, const int* __restrict__ flaglist,
                 double* __restrict__ nv64)
{
  const int nf    = *flagcnt;
  const int lane  = threadIdx.x & 63;
  const int wslot = (blockIdx.x * 512 + threadIdx.x) >> 6;
  const int nwav  = (gridDim.x * 512) >> 6;
  const int total = nf * 64;

  for (int w = wslot; w < total; w += nwav) {
    const int i = w >> 6, e = w & 63;
    const int t = flaglist[i];
    const float* xr  = x  + (size_t)t * KDIM + lane * 4;
    const float* wrr = Wr + (size_t)e * KDIM + lane * 4;
    const float* wnr = Wn + (size_t)e * KDIM + lane * 4;
    double a0 = 0, a1 = 0, c0 = 0, c1 = 0;
#pragma unroll
    for (int q = 0; q < 8; ++q) {
      const float4 xv = *(const float4*)(xr  + q * 256);
      const float4 wv = *(const float4*)(wrr + q * 256);
      const float4 nv = *(const float4*)(wnr + q * 256);
      a0 = fma((double)xv.x, (double)wv.x, a0);
      a1 = fma((double)xv.y, (double)wv.y, a1);
      a0 = fma((double)xv.z, (double)wv.z, a0);
      a1 = fma((double)xv.w, (double)wv.w, a1);
      c0 = fma((double)xv.x, (double)nv.x, c0);
      c1 = fma((double)xv.y, (double)nv.y, c1);
      c0 = fma((double)xv.z, (double)nv.z, c0);
      c1 = fma((double)xv.w, (double)nv.w, c1);
    }
    double ar = a0 + a1, an = c0 + c1;
#pragma unroll
    for (int d = 32; d; d >>= 1) {
      ar += __shfl_xor(ar, d);
      an += __shfl_xor(an, d);
    }
    if (lane == 0) {
      const double rte = ar + (double)br[e];
      const double zz  = an + (double)bn[e];
      const double spd = fmax(zz, 0.0) + log1p(exp(-fabs(zz)));
      nv64[(size_t)i * 64 + e] = rte + (double)noise[(size_t)t * NEXP + e] * spd;
    }
  }
}

// one wave per flagged token: proven fp64 softmax/top-8 tail
__global__ __launch_bounds__(512)
void refine_final(const double* __restrict__ nv64,
                  const int* __restrict__ flagcnt, const int* __restrict__ flaglist,
                  float* __restrict__ out_w, float* __restrict__ out_i,
                  float* __restrict__ out_s)
{
  const int nf    = *flagcnt;
  const int lane  = threadIdx.x & 63;
  const int wslot = (blockIdx.x * 512 + threadIdx.x) >> 6;
  const int nwav  = (gridDim.x * 512) >> 6;

  for (int i = wslot; i < nf; i += nwav) {
    const int t = flaglist[i];
    const double v64 = nv64[(size_t)i * 64 + lane];
    double md = v64;
#pragma unroll
    for (int d = 32; d; d >>= 1) md = fmax(md, __shfl_xor(md, d));
    const double pe = exp(v64 - md);
    double sd = pe;
#pragma unroll
    for (int d = 32; d; d >>= 1) sd += __shfl_xor(sd, d);
    out_s[(size_t)t * NEXP + lane] = (float)(pe / sd);

    double curd = v64;
    double pv8[8]; int pi8[8]; double wsd = 0.0;
#pragma unroll
    for (int it = 0; it < 8; ++it) {
      double mx = curd;
#pragma unroll
      for (int d = 32; d; d >>= 1) mx = fmax(mx, __shfl_xor(mx, d));
      const unsigned long long b = __ballot(curd == mx);
      const int li = __ffsll(b) - 1;
      pv8[it] = __shfl(pe, li); pi8[it] = li; wsd += pv8[it];
      if (lane == li) curd = -1e300;
    }
    if (lane < 8) {
      out_w[(size_t)t * 8 + lane] = (float)(pv8[lane] / wsd);
      out_i[(size_t)t * 8 + lane] = (float)pi8[lane];
    }
  }
}

extern "C" void kernel_launch(void* const* d_in, const int* in_sizes, int n_in,
                              void* d_out, int out_size, void* d_ws, size_t ws_size,
                              hipStream_t stream) {
  const float* x     = (const float*)d_in[0];
  const float* Wr    = (const float*)d_in[1];
  const float* br    = (const float*)d_in[2];
  const float* Wn    = (const float*)d_in[3];
  const float* bn    = (const float*)d_in[4];
  const float* noise = (const float*)d_in[5];

  const int M = in_sizes[0] / KDIM;                  // 16384 tokens

  const size_t fixed = (1 << 20) + ((size_t)M + 1) * 4;
  int nsplit = 2;
  if (ws_size >= (size_t)4 * M * 128 * 4 + fixed) nsplit = 4;

  float*  partials = (float*)d_ws;                   // [nsplit][M][128]
  double* nv64     = (double*)d_ws;                  // aliases (dead after epi)
  ushort* Wpk      = (ushort*)(partials + (size_t)nsplit * M * 128);  // 1 MB
  int*    flagcnt  = (int*)(Wpk + (size_t)64 * 8192);
  int*    flaglist = flagcnt + 1;

  float* out   = (float*)d_out;
  float* out_w = out;                                // [M,8]
  float* out_i = out + (size_t)M * 8;                // [M,8] indices as floats
  float* out_s = out + (size_t)M * 16;               // [M,64]

  convert_w<<<dim3(128), dim3(256), 0, stream>>>(Wr, Wn, Wpk, flagcnt);
  gemm_k1<<<dim3(M / BM, nsplit), dim3(512), 0, stream>>>(x, Wpk, partials, M);
  epi_fast<<<dim3(M / 8), dim3(512), 0, stream>>>(partials, M, nsplit, br, bn,
                                                  noise, out_w, out_i, out_s,
                                                  flagcnt, flaglist);
  refine_dots<<<dim3(1024), dim3(512), 0, stream>>>(x, Wr, Wn, br, bn, noise,
                                                    flagcnt, flaglist, nv64);
  refine_final<<<dim3(256), dim3(512), 0, stream>>>(nv64, flagcnt, flaglist,
                                                    out_w, out_i, out_s);
}